// Round 1
// baseline (1320.595 us; speedup 1.0000x reference)
//
#include <hip/hip_runtime.h>
#include <cstdio>
#include <cstdint>

// ---------------- types / helpers ----------------
typedef __attribute__((ext_vector_type(4))) float floatx4;
typedef __attribute__((ext_vector_type(8))) short short8;

constexpr int T_TOK = 8192;   // B*S
constexpr int DIM   = 1024;   // D
constexpr int NEXP  = 8;      // E
constexpr int HID   = 4096;   // H
constexpr int NSLOT = 16384;  // 2*T (top-2)

__device__ __forceinline__ unsigned short f2bf(float f) {
  union { float f; unsigned int i; } c; c.f = f;
  unsigned int i = c.i;
  unsigned int r = (i + 0x7fffu + ((i >> 16) & 1u)) >> 16;
  return (unsigned short)r;
}
__device__ __forceinline__ float bf2f(unsigned short u) {
  union { unsigned int i; float f; } c; c.i = ((unsigned int)u) << 16;
  return c.f;
}
__device__ __forceinline__ void ld16(const void* g, void* l) {
  __builtin_amdgcn_global_load_lds(
      (const __attribute__((address_space(1))) unsigned int*)g,
      (__attribute__((address_space(3))) unsigned int*)l, 16, 0, 0);
}

// ---------------- convert x -> bf16 ----------------
__global__ __launch_bounds__(256) void convert_x_kernel(
    const float* __restrict__ x, unsigned short* __restrict__ xb, int n4) {
  int i = blockIdx.x * 256 + threadIdx.x;
  if (i < n4) {
    float4 v = ((const float4*)x)[i];
    ushort4 o;
    o.x = f2bf(v.x); o.y = f2bf(v.y); o.z = f2bf(v.z); o.w = f2bf(v.w);
    ((ushort4*)xb)[i] = o;
  }
}

// ------------- transpose+convert weights: in fp32 [E][R][C] -> out bf16 [E][C][R] -------------
__global__ __launch_bounds__(256) void transpose_convert_kernel(
    const float* __restrict__ in, unsigned short* __restrict__ out, int R, int C) {
  __shared__ float tile[32][33];
  int e = blockIdx.z;
  const float* ip = in + (size_t)e * R * C;
  unsigned short* op = out + (size_t)e * R * C;
  int tx = threadIdx.x & 31;
  int ty = threadIdx.x >> 5;              // 0..7
  int cb = blockIdx.x * 32, rb = blockIdx.y * 32;
#pragma unroll
  for (int i = 0; i < 4; ++i) {
    int r = rb + ty + i * 8;
    tile[ty + i * 8][tx] = ip[(size_t)r * C + cb + tx];
  }
  __syncthreads();
#pragma unroll
  for (int i = 0; i < 4; ++i) {
    int c = cb + ty + i * 8;
    op[(size_t)c * R + rb + tx] = f2bf(tile[tx][ty + i * 8]);
  }
}

// ---------------- router: logits, softmax, top-2, gates, counts, prob sums ----------------
__global__ __launch_bounds__(1024) void router_kernel(
    const float* __restrict__ x, const float* __restrict__ rw, const float* __restrict__ rb,
    int* __restrict__ te, float* __restrict__ tg,
    int* __restrict__ counts, float* __restrict__ prob_sums) {
  __shared__ float ps[8];
  int tid = threadIdx.x;
  if (tid < 8) ps[tid] = 0.0f;
  __syncthreads();
  int wid = tid >> 6, lane = tid & 63;
  int t = blockIdx.x * 16 + wid;
  const float* xt = x + (size_t)t * DIM;
  float acc[8] = {0, 0, 0, 0, 0, 0, 0, 0};
  for (int d = lane; d < DIM; d += 64) {
    float xv = xt[d];
    const float4* rp = (const float4*)(rw + d * 8);
    float4 r0 = rp[0], r1 = rp[1];
    acc[0] += xv * r0.x; acc[1] += xv * r0.y; acc[2] += xv * r0.z; acc[3] += xv * r0.w;
    acc[4] += xv * r1.x; acc[5] += xv * r1.y; acc[6] += xv * r1.z; acc[7] += xv * r1.w;
  }
#pragma unroll
  for (int e = 0; e < 8; ++e)
#pragma unroll
    for (int s = 32; s > 0; s >>= 1) acc[e] += __shfl_xor(acc[e], s, 64);
  if (lane == 0) {
    float lg[8];
#pragma unroll
    for (int e = 0; e < 8; ++e) lg[e] = acc[e] + rb[e];
    float mx = lg[0];
#pragma unroll
    for (int e = 1; e < 8; ++e) mx = fmaxf(mx, lg[e]);
    float p[8], sum = 0.0f;
#pragma unroll
    for (int e = 0; e < 8; ++e) { p[e] = __expf(lg[e] - mx); sum += p[e]; }
    float inv = 1.0f / sum;
#pragma unroll
    for (int e = 0; e < 8; ++e) p[e] *= inv;
    int i0 = 0; float v0 = p[0];
#pragma unroll
    for (int e = 1; e < 8; ++e) if (p[e] > v0) { v0 = p[e]; i0 = e; }
    int i1 = -1; float v1 = -1.0f;
#pragma unroll
    for (int e = 0; e < 8; ++e) if (e != i0 && p[e] > v1) { v1 = p[e]; i1 = e; }
    float gs = 1.0f / (v0 + v1);
    te[2 * t] = i0; te[2 * t + 1] = i1;
    tg[2 * t] = v0 * gs; tg[2 * t + 1] = v1 * gs;
    atomicAdd(&counts[i0], 1);
    atomicAdd(&counts[i1], 1);
#pragma unroll
    for (int e = 0; e < 8; ++e) atomicAdd(&ps[e], p[e]);
  }
  __syncthreads();
  if (tid < 8) atomicAdd(&prob_sums[tid], ps[tid]);
}

// ---------------- offsets prefix + load-balance loss ----------------
__global__ void finalize_kernel(const int* __restrict__ counts, int* __restrict__ offsets,
                                int* __restrict__ cursor, const float* __restrict__ prob_sums,
                                float* __restrict__ loss_out) {
  if (threadIdx.x == 0 && blockIdx.x == 0) {
    int off = 0;
#pragma unroll
    for (int e = 0; e < 8; ++e) { offsets[e] = off; cursor[e] = off; off += counts[e]; }
    float loss = 0.0f;
#pragma unroll
    for (int e = 0; e < 8; ++e) {
      float mp = prob_sums[e] * (1.0f / (float)T_TOK);
      loss += mp * logf(mp);
    }
    *loss_out = 8.0f * loss;
  }
}

// ---------------- slot assignment (packed per-expert lists) ----------------
__global__ __launch_bounds__(256) void assign_kernel(
    const int* __restrict__ te, int* __restrict__ cursor,
    int* __restrict__ tok_slot, int* __restrict__ idx_map) {
  int t = blockIdx.x * 256 + threadIdx.x;
#pragma unroll
  for (int k = 0; k < 2; ++k) {
    int e = te[2 * t + k];
    int slot = atomicAdd(&cursor[e], 1);
    tok_slot[2 * t + k] = slot;
    idx_map[slot] = t;
  }
}

// ---------------- MFMA GEMM: 128x128 tile, BK=64, bf16, m97-style staging ----------------
// A rows: INDIRECT -> xb[idx_map[slot]] (gather), else h[slot] (packed).
// Bt: [E][NTOT][KTOT] (pre-transposed so fragment reads are contiguous in k).
template <bool INDIRECT, bool GELU, int KTOT, int NTOT>
__global__ __launch_bounds__(256) void moe_gemm_kernel(
    const unsigned short* __restrict__ A, const unsigned short* __restrict__ Bt,
    const float* __restrict__ bias, unsigned short* __restrict__ Out,
    const int* __restrict__ counts, const int* __restrict__ offsets,
    const int* __restrict__ idx_map) {
  int e = blockIdx.z;
  int cnt = counts[e];
  int tm = blockIdx.y;
  if (tm * 128 >= cnt) return;
  int off = offsets[e];
  int tn = blockIdx.x;
  int tid = threadIdx.x;

  __shared__ __align__(16) unsigned short As[128 * 64];
  __shared__ __align__(16) unsigned short Bs[128 * 64];

  const int seg  = tid & 7;    // 8-elem k-segment within row
  const int rsub = tid >> 3;   // 0..31 row within 32-row chunk
  const int kseg = seg * 8;

  const unsigned short* aptr[4];
  const unsigned short* bptr[4];
  const unsigned short* Bte = Bt + (size_t)e * NTOT * KTOT;
#pragma unroll
  for (int c = 0; c < 4; ++c) {
    int r = c * 32 + rsub;                 // 0..127 tile row
    int slot = off + tm * 128 + r;
    long arow;
    if (INDIRECT) {
      int s = slot <= (NSLOT - 1) ? slot : (NSLOT - 1);
      arow = (long)idx_map[s] * KTOT;
    } else {
      arow = (long)slot * KTOT;
    }
    aptr[c] = A + arow + kseg;
    bptr[c] = Bte + (size_t)(tn * 128 + r) * KTOT + kseg;
  }
  char* ldsA = (char*)As + tid * 16;
  char* ldsB = (char*)Bs + tid * 16;

  floatx4 acc[4][4];
#pragma unroll
  for (int i = 0; i < 4; ++i)
#pragma unroll
    for (int j = 0; j < 4; ++j) acc[i][j] = (floatx4){0.f, 0.f, 0.f, 0.f};

  int wid = tid >> 6, lane = tid & 63;
  int wm = wid & 1, wn = wid >> 1;
  int m16 = lane & 15, q = lane >> 4;

#pragma unroll 1
  for (int k0 = 0; k0 < KTOT; k0 += 64) {
#pragma unroll
    for (int c = 0; c < 4; ++c) {
      ld16(aptr[c] + k0, ldsA + c * 4096);
      ld16(bptr[c] + k0, ldsB + c * 4096);
    }
    __syncthreads();
    short8 aF[4][2], bF[4][2];
#pragma unroll
    for (int mi = 0; mi < 4; ++mi)
#pragma unroll
      for (int kk = 0; kk < 2; ++kk)
        aF[mi][kk] = *(const short8*)&As[(wm * 64 + mi * 16 + m16) * 64 + kk * 32 + q * 8];
#pragma unroll
    for (int ni = 0; ni < 4; ++ni)
#pragma unroll
      for (int kk = 0; kk < 2; ++kk)
        bF[ni][kk] = *(const short8*)&Bs[(wn * 64 + ni * 16 + m16) * 64 + kk * 32 + q * 8];
#pragma unroll
    for (int kk = 0; kk < 2; ++kk)
#pragma unroll
      for (int mi = 0; mi < 4; ++mi)
#pragma unroll
        for (int ni = 0; ni < 4; ++ni)
          acc[mi][ni] = __builtin_amdgcn_mfma_f32_16x16x32_bf16(
              aF[mi][kk], bF[ni][kk], acc[mi][ni], 0, 0, 0);
    __syncthreads();
  }

  // epilogue: row-masked (partial tiles must not clobber next expert's packed rows)
  int rowlim = cnt - tm * 128;
#pragma unroll
  for (int ni = 0; ni < 4; ++ni) {
    int col = tn * 128 + wn * 64 + ni * 16 + m16;
    float bv = bias[e * NTOT + col];
#pragma unroll
    for (int mi = 0; mi < 4; ++mi) {
#pragma unroll
      for (int r = 0; r < 4; ++r) {
        int rr = wm * 64 + mi * 16 + q * 4 + r;
        if (rr < rowlim) {
          float v = acc[mi][ni][r] + bv;
          if (GELU) v = 0.5f * v * (1.0f + erff(v * 0.70710678118654752f));
          Out[(size_t)(off + tm * 128 + rr) * NTOT + col] = f2bf(v);
        }
      }
    }
  }
}

// ---------------- combine: out[t] = g0*y[s0] + g1*y[s1] ----------------
__global__ __launch_bounds__(256) void combine_kernel(
    const unsigned short* __restrict__ y, const int* __restrict__ tok_slot,
    const float* __restrict__ tg, float* __restrict__ out) {
  int t = blockIdx.x;
  int s0 = tok_slot[2 * t], s1 = tok_slot[2 * t + 1];
  float g0 = tg[2 * t], g1 = tg[2 * t + 1];
  int c = threadIdx.x * 4;
  ushort4 a = *(const ushort4*)&y[(size_t)s0 * DIM + c];
  ushort4 b = *(const ushort4*)&y[(size_t)s1 * DIM + c];
  float4 o;
  o.x = g0 * bf2f(a.x) + g1 * bf2f(b.x);
  o.y = g0 * bf2f(a.y) + g1 * bf2f(b.y);
  o.z = g0 * bf2f(a.z) + g1 * bf2f(b.z);
  o.w = g0 * bf2f(a.w) + g1 * bf2f(b.w);
  ((float4*)(out + (size_t)t * DIM))[threadIdx.x] = o;
}

// ---------------- host ----------------
extern "C" void kernel_launch(void* const* d_in, const int* in_sizes, int n_in,
                              void* d_out, int out_size, void* d_ws, size_t ws_size,
                              hipStream_t stream) {
  const float* x  = (const float*)d_in[0];
  const float* rw = (const float*)d_in[1];
  const float* rb = (const float*)d_in[2];
  const float* w1 = (const float*)d_in[3];
  const float* b1 = (const float*)d_in[4];
  const float* w2 = (const float*)d_in[5];
  const float* b2 = (const float*)d_in[6];
  float* out = (float*)d_out;
  float* loss_out = out + (out_size - 1);

  size_t o = 0;
  char* wsb = (char*)d_ws;
  auto take = [&](size_t bytes) -> char* {
    char* p = wsb + o;
    o += (bytes + 255) & ~(size_t)255;
    return p;
  };
  unsigned short* w1t = (unsigned short*)take((size_t)NEXP * HID * DIM * 2);  // [E][H][D]
  unsigned short* w2t = (unsigned short*)take((size_t)NEXP * HID * DIM * 2);  // [E][D][H]
  unsigned short* xb  = (unsigned short*)take((size_t)T_TOK * DIM * 2);
  unsigned short* hbf = (unsigned short*)take((size_t)NSLOT * HID * 2 + (1u << 20)); // +1MB read-overrun pad
  unsigned short* ybf = (unsigned short*)take((size_t)NSLOT * DIM * 2);
  int*   te       = (int*)take(NSLOT * 4);
  float* tg       = (float*)take(NSLOT * 4);
  int*   tok_slot = (int*)take(NSLOT * 4);
  int*   idx_map  = (int*)take(NSLOT * 4);
  char*  smallb   = take(256);
  int*   counts    = (int*)smallb;
  float* prob_sums = (float*)(smallb + 32);
  int*   offsets   = (int*)(smallb + 64);
  int*   cursor    = (int*)(smallb + 96);

  if (o > ws_size) {
    fprintf(stderr, "kernel_launch: ws too small, need %zu have %zu\n", o, ws_size);
    return;
  }

  hipMemsetAsync(smallb, 0, 64, stream);  // counts + prob_sums

  // conversions (independent of router)
  convert_x_kernel<<<(T_TOK * DIM / 4 + 255) / 256, 256, 0, stream>>>(x, xb, T_TOK * DIM / 4);
  // w1: [E][D=1024][H=4096] -> w1t [E][H][D]
  transpose_convert_kernel<<<dim3(HID / 32, DIM / 32, NEXP), 256, 0, stream>>>(w1, w1t, DIM, HID);
  // w2: [E][H=4096][D=1024] -> w2t [E][D][H]
  transpose_convert_kernel<<<dim3(DIM / 32, HID / 32, NEXP), 256, 0, stream>>>(w2, w2t, HID, DIM);

  router_kernel<<<T_TOK / 16, 1024, 0, stream>>>(x, rw, rb, te, tg, counts, prob_sums);
  finalize_kernel<<<1, 64, 0, stream>>>(counts, offsets, cursor, prob_sums, loss_out);
  assign_kernel<<<T_TOK / 256, 256, 0, stream>>>(te, cursor, tok_slot, idx_map);

  // GEMM1: h = gelu(x_gathered @ w1 + b1)   [slots x 4096], K=1024
  moe_gemm_kernel<true, true, DIM, HID>
      <<<dim3(HID / 128, NSLOT / 128 * 0 + 64, NEXP), 256, 0, stream>>>(
          xb, w1t, b1, hbf, counts, offsets, idx_map);
  // GEMM2: y = h @ w2 + b2                  [slots x 1024], K=4096
  moe_gemm_kernel<false, false, HID, DIM>
      <<<dim3(DIM / 128, 64, NEXP), 256, 0, stream>>>(
          hbf, w2t, b2, ybf, counts, offsets, idx_map);

  combine_kernel<<<T_TOK, 256, 0, stream>>>(ybf, tok_slot, tg, out);
}

// Round 2
// 1276.480 us; speedup vs baseline: 1.0346x; 1.0346x over previous
//
#include <hip/hip_runtime.h>
#include <cstdio>
#include <cstdint>

// ---------------- types / helpers ----------------
typedef __attribute__((ext_vector_type(4))) float floatx4;
typedef __attribute__((ext_vector_type(8))) short short8;

constexpr int T_TOK = 8192;   // B*S
constexpr int DIM   = 1024;   // D
constexpr int NEXP  = 8;      // E
constexpr int HID   = 4096;   // H
constexpr int NSLOT = 16384;  // 2*T (top-2)

__device__ __forceinline__ unsigned short f2bf(float f) {
  union { float f; unsigned int i; } c; c.f = f;
  unsigned int i = c.i;
  unsigned int r = (i + 0x7fffu + ((i >> 16) & 1u)) >> 16;
  return (unsigned short)r;
}
__device__ __forceinline__ float bf2f(unsigned short u) {
  union { unsigned int i; float f; } c; c.i = ((unsigned int)u) << 16;
  return c.f;
}
__device__ __forceinline__ void ld16(const void* g, void* l) {
  __builtin_amdgcn_global_load_lds(
      (const __attribute__((address_space(1))) unsigned int*)g,
      (__attribute__((address_space(3))) unsigned int*)l, 16, 0, 0);
}

// ---------------- convert x -> bf16 ----------------
__global__ __launch_bounds__(256) void convert_x_kernel(
    const float* __restrict__ x, unsigned short* __restrict__ xb, int n4) {
  int i = blockIdx.x * 256 + threadIdx.x;
  if (i < n4) {
    float4 v = ((const float4*)x)[i];
    ushort4 o;
    o.x = f2bf(v.x); o.y = f2bf(v.y); o.z = f2bf(v.z); o.w = f2bf(v.w);
    ((ushort4*)xb)[i] = o;
  }
}

// ------------- transpose+convert weights: in fp32 [E][R][C] -> out bf16 [E][C][R] -------------
__global__ __launch_bounds__(256) void transpose_convert_kernel(
    const float* __restrict__ in, unsigned short* __restrict__ out, int R, int C) {
  __shared__ float tile[32][33];
  int e = blockIdx.z;
  const float* ip = in + (size_t)e * R * C;
  unsigned short* op = out + (size_t)e * R * C;
  int tx = threadIdx.x & 31;
  int ty = threadIdx.x >> 5;              // 0..7
  int cb = blockIdx.x * 32, rb = blockIdx.y * 32;
#pragma unroll
  for (int i = 0; i < 4; ++i) {
    int r = rb + ty + i * 8;
    tile[ty + i * 8][tx] = ip[(size_t)r * C + cb + tx];
  }
  __syncthreads();
#pragma unroll
  for (int i = 0; i < 4; ++i) {
    int c = cb + ty + i * 8;
    op[(size_t)c * R + rb + tx] = f2bf(tile[tx][ty + i * 8]);
  }
}

// ---------------- router: logits, softmax, top-2, gates, counts, prob sums ----------------
__global__ __launch_bounds__(1024) void router_kernel(
    const float* __restrict__ x, const float* __restrict__ rw, const float* __restrict__ rb,
    int* __restrict__ te, float* __restrict__ tg,
    int* __restrict__ counts, float* __restrict__ prob_sums) {
  __shared__ float ps[8];
  int tid = threadIdx.x;
  if (tid < 8) ps[tid] = 0.0f;
  __syncthreads();
  int wid = tid >> 6, lane = tid & 63;
  int t = blockIdx.x * 16 + wid;
  const float* xt = x + (size_t)t * DIM;
  float acc[8] = {0, 0, 0, 0, 0, 0, 0, 0};
  for (int d = lane; d < DIM; d += 64) {
    float xv = xt[d];
    const float4* rp = (const float4*)(rw + d * 8);
    float4 r0 = rp[0], r1 = rp[1];
    acc[0] += xv * r0.x; acc[1] += xv * r0.y; acc[2] += xv * r0.z; acc[3] += xv * r0.w;
    acc[4] += xv * r1.x; acc[5] += xv * r1.y; acc[6] += xv * r1.z; acc[7] += xv * r1.w;
  }
#pragma unroll
  for (int e = 0; e < 8; ++e)
#pragma unroll
    for (int s = 32; s > 0; s >>= 1) acc[e] += __shfl_xor(acc[e], s, 64);
  if (lane == 0) {
    float lg[8];
#pragma unroll
    for (int e = 0; e < 8; ++e) lg[e] = acc[e] + rb[e];
    float mx = lg[0];
#pragma unroll
    for (int e = 1; e < 8; ++e) mx = fmaxf(mx, lg[e]);
    float p[8], sum = 0.0f;
#pragma unroll
    for (int e = 0; e < 8; ++e) { p[e] = __expf(lg[e] - mx); sum += p[e]; }
    float inv = 1.0f / sum;
#pragma unroll
    for (int e = 0; e < 8; ++e) p[e] *= inv;
    int i0 = 0; float v0 = p[0];
#pragma unroll
    for (int e = 1; e < 8; ++e) if (p[e] > v0) { v0 = p[e]; i0 = e; }
    int i1 = -1; float v1 = -1.0f;
#pragma unroll
    for (int e = 0; e < 8; ++e) if (e != i0 && p[e] > v1) { v1 = p[e]; i1 = e; }
    float gs = 1.0f / (v0 + v1);
    te[2 * t] = i0; te[2 * t + 1] = i1;
    tg[2 * t] = v0 * gs; tg[2 * t + 1] = v1 * gs;
    atomicAdd(&counts[i0], 1);
    atomicAdd(&counts[i1], 1);
#pragma unroll
    for (int e = 0; e < 8; ++e) atomicAdd(&ps[e], p[e]);
  }
  __syncthreads();
  if (tid < 8) atomicAdd(&prob_sums[tid], ps[tid]);
}

// ---------------- offsets prefix + load-balance loss ----------------
__global__ void finalize_kernel(const int* __restrict__ counts, int* __restrict__ offsets,
                                int* __restrict__ cursor, const float* __restrict__ prob_sums,
                                float* __restrict__ loss_out) {
  if (threadIdx.x == 0 && blockIdx.x == 0) {
    int off = 0;
#pragma unroll
    for (int e = 0; e < 8; ++e) { offsets[e] = off; cursor[e] = off; off += counts[e]; }
    float loss = 0.0f;
#pragma unroll
    for (int e = 0; e < 8; ++e) {
      float mp = prob_sums[e] * (1.0f / (float)T_TOK);
      loss += mp * logf(mp);
    }
    *loss_out = 8.0f * loss;
  }
}

// ---------------- slot assignment (packed per-expert lists) ----------------
__global__ __launch_bounds__(256) void assign_kernel(
    const int* __restrict__ te, int* __restrict__ cursor,
    int* __restrict__ tok_slot, int* __restrict__ idx_map) {
  int t = blockIdx.x * 256 + threadIdx.x;
#pragma unroll
  for (int k = 0; k < 2; ++k) {
    int e = te[2 * t + k];
    int slot = atomicAdd(&cursor[e], 1);
    tok_slot[2 * t + k] = slot;
    idx_map[slot] = t;
  }
}

// ---------------- MFMA GEMM: 128x128 tile, BK=64, bf16, m97-style staging ----------------
// A rows: INDIRECT -> xb[idx_map[slot]] (gather), else h[slot] (packed).
// Bt: [E][NTOT][KTOT] (pre-transposed so fragment reads are contiguous in k).
// LDS k-segment XOR swizzle: LDS position seg' of row r holds global segment
// seg' ^ (r&7). Row stride is 128 B (=32 banks), so unswizzled fragment reads
// were 16-way bank-conflicted (R1: 5.19e7 SQ_LDS_BANK_CONFLICT, MfmaUtil 14.5%).
template <bool INDIRECT, bool GELU, int KTOT, int NTOT>
__global__ __launch_bounds__(256) void moe_gemm_kernel(
    const unsigned short* __restrict__ A, const unsigned short* __restrict__ Bt,
    const float* __restrict__ bias, unsigned short* __restrict__ Out,
    const int* __restrict__ counts, const int* __restrict__ offsets,
    const int* __restrict__ idx_map) {
  int e = blockIdx.z;
  int cnt = counts[e];
  int tm = blockIdx.y;
  if (tm * 128 >= cnt) return;
  int off = offsets[e];
  int tn = blockIdx.x;
  int tid = threadIdx.x;

  __shared__ __align__(16) unsigned short As[128 * 64];
  __shared__ __align__(16) unsigned short Bs[128 * 64];

  const int segp = tid & 7;    // LDS 8-elem k-segment position within row
  const int rsub = tid >> 3;   // 0..31 row within 32-row chunk
  const int kseg = (segp ^ (rsub & 7)) * 8;  // swizzled global k-segment

  const unsigned short* aptr[4];
  const unsigned short* bptr[4];
  const unsigned short* Bte = Bt + (size_t)e * NTOT * KTOT;
#pragma unroll
  for (int c = 0; c < 4; ++c) {
    int r = c * 32 + rsub;                 // 0..127 tile row (r&7 == rsub&7)
    int slot = off + tm * 128 + r;
    long arow;
    if (INDIRECT) {
      int s = slot <= (NSLOT - 1) ? slot : (NSLOT - 1);
      arow = (long)idx_map[s] * KTOT;
    } else {
      arow = (long)slot * KTOT;
    }
    aptr[c] = A + arow + kseg;
    bptr[c] = Bte + (size_t)(tn * 128 + r) * KTOT + kseg;
  }
  char* ldsA = (char*)As + tid * 16;
  char* ldsB = (char*)Bs + tid * 16;

  floatx4 acc[4][4];
#pragma unroll
  for (int i = 0; i < 4; ++i)
#pragma unroll
    for (int j = 0; j < 4; ++j) acc[i][j] = (floatx4){0.f, 0.f, 0.f, 0.f};

  int wid = tid >> 6, lane = tid & 63;
  int wm = wid & 1, wn = wid >> 1;
  int m16 = lane & 15, q = lane >> 4;
  int sw = m16 & 7;  // row&7 for all fragment rows this lane reads

#pragma unroll 1
  for (int k0 = 0; k0 < KTOT; k0 += 64) {
#pragma unroll
    for (int c = 0; c < 4; ++c) {
      ld16(aptr[c] + k0, ldsA + c * 4096);
      ld16(bptr[c] + k0, ldsB + c * 4096);
    }
    __syncthreads();
    short8 aF[4][2], bF[4][2];
#pragma unroll
    for (int mi = 0; mi < 4; ++mi)
#pragma unroll
      for (int kk = 0; kk < 2; ++kk)
        aF[mi][kk] = *(const short8*)&As[(wm * 64 + mi * 16 + m16) * 64 +
                                         ((kk * 4 + q) ^ sw) * 8];
#pragma unroll
    for (int ni = 0; ni < 4; ++ni)
#pragma unroll
      for (int kk = 0; kk < 2; ++kk)
        bF[ni][kk] = *(const short8*)&Bs[(wn * 64 + ni * 16 + m16) * 64 +
                                         ((kk * 4 + q) ^ sw) * 8];
#pragma unroll
    for (int kk = 0; kk < 2; ++kk)
#pragma unroll
      for (int mi = 0; mi < 4; ++mi)
#pragma unroll
        for (int ni = 0; ni < 4; ++ni)
          acc[mi][ni] = __builtin_amdgcn_mfma_f32_16x16x32_bf16(
              aF[mi][kk], bF[ni][kk], acc[mi][ni], 0, 0, 0);
    __syncthreads();
  }

  // epilogue: row-masked (partial tiles must not clobber next expert's packed rows)
  int rowlim = cnt - tm * 128;
#pragma unroll
  for (int ni = 0; ni < 4; ++ni) {
    int col = tn * 128 + wn * 64 + ni * 16 + m16;
    float bv = bias[e * NTOT + col];
#pragma unroll
    for (int mi = 0; mi < 4; ++mi) {
#pragma unroll
      for (int r = 0; r < 4; ++r) {
        int rr = wm * 64 + mi * 16 + q * 4 + r;
        if (rr < rowlim) {
          float v = acc[mi][ni][r] + bv;
          if (GELU) v = 0.5f * v * (1.0f + erff(v * 0.70710678118654752f));
          Out[(size_t)(off + tm * 128 + rr) * NTOT + col] = f2bf(v);
        }
      }
    }
  }
}

// ---------------- combine: out[t] = g0*y[s0] + g1*y[s1] ----------------
__global__ __launch_bounds__(256) void combine_kernel(
    const unsigned short* __restrict__ y, const int* __restrict__ tok_slot,
    const float* __restrict__ tg, float* __restrict__ out) {
  int t = blockIdx.x;
  int s0 = tok_slot[2 * t], s1 = tok_slot[2 * t + 1];
  float g0 = tg[2 * t], g1 = tg[2 * t + 1];
  int c = threadIdx.x * 4;
  ushort4 a = *(const ushort4*)&y[(size_t)s0 * DIM + c];
  ushort4 b = *(const ushort4*)&y[(size_t)s1 * DIM + c];
  float4 o;
  o.x = g0 * bf2f(a.x) + g1 * bf2f(b.x);
  o.y = g0 * bf2f(a.y) + g1 * bf2f(b.y);
  o.z = g0 * bf2f(a.z) + g1 * bf2f(b.z);
  o.w = g0 * bf2f(a.w) + g1 * bf2f(b.w);
  ((float4*)(out + (size_t)t * DIM))[threadIdx.x] = o;
}

// ---------------- host ----------------
extern "C" void kernel_launch(void* const* d_in, const int* in_sizes, int n_in,
                              void* d_out, int out_size, void* d_ws, size_t ws_size,
                              hipStream_t stream) {
  const float* x  = (const float*)d_in[0];
  const float* rw = (const float*)d_in[1];
  const float* rb = (const float*)d_in[2];
  const float* w1 = (const float*)d_in[3];
  const float* b1 = (const float*)d_in[4];
  const float* w2 = (const float*)d_in[5];
  const float* b2 = (const float*)d_in[6];
  float* out = (float*)d_out;
  float* loss_out = out + (out_size - 1);

  size_t o = 0;
  char* wsb = (char*)d_ws;
  auto take = [&](size_t bytes) -> char* {
    char* p = wsb + o;
    o += (bytes + 255) & ~(size_t)255;
    return p;
  };
  unsigned short* w1t = (unsigned short*)take((size_t)NEXP * HID * DIM * 2);  // [E][H][D]
  unsigned short* w2t = (unsigned short*)take((size_t)NEXP * HID * DIM * 2);  // [E][D][H]
  unsigned short* xb  = (unsigned short*)take((size_t)T_TOK * DIM * 2);
  unsigned short* hbf = (unsigned short*)take((size_t)NSLOT * HID * 2 + (1u << 20)); // +1MB read-overrun pad
  unsigned short* ybf = (unsigned short*)take((size_t)NSLOT * DIM * 2);
  int*   te       = (int*)take(NSLOT * 4);
  float* tg       = (float*)take(NSLOT * 4);
  int*   tok_slot = (int*)take(NSLOT * 4);
  int*   idx_map  = (int*)take(NSLOT * 4);
  char*  smallb   = take(256);
  int*   counts    = (int*)smallb;
  float* prob_sums = (float*)(smallb + 32);
  int*   offsets   = (int*)(smallb + 64);
  int*   cursor    = (int*)(smallb + 96);

  if (o > ws_size) {
    fprintf(stderr, "kernel_launch: ws too small, need %zu have %zu\n", o, ws_size);
    return;
  }

  hipMemsetAsync(smallb, 0, 64, stream);  // counts + prob_sums

  // conversions (independent of router)
  convert_x_kernel<<<(T_TOK * DIM / 4 + 255) / 256, 256, 0, stream>>>(x, xb, T_TOK * DIM / 4);
  // w1: [E][D=1024][H=4096] -> w1t [E][H][D]
  transpose_convert_kernel<<<dim3(HID / 32, DIM / 32, NEXP), 256, 0, stream>>>(w1, w1t, DIM, HID);
  // w2: [E][H=4096][D=1024] -> w2t [E][D][H]
  transpose_convert_kernel<<<dim3(DIM / 32, HID / 32, NEXP), 256, 0, stream>>>(w2, w2t, HID, DIM);

  router_kernel<<<T_TOK / 16, 1024, 0, stream>>>(x, rw, rb, te, tg, counts, prob_sums);
  finalize_kernel<<<1, 64, 0, stream>>>(counts, offsets, cursor, prob_sums, loss_out);
  assign_kernel<<<T_TOK / 256, 256, 0, stream>>>(te, cursor, tok_slot, idx_map);

  // GEMM1: h = gelu(x_gathered @ w1 + b1)   [slots x 4096], K=1024
  moe_gemm_kernel<true, true, DIM, HID>
      <<<dim3(HID / 128, NSLOT / 128, NEXP), 256, 0, stream>>>(
          xb, w1t, b1, hbf, counts, offsets, idx_map);
  // GEMM2: y = h @ w2 + b2                  [slots x 1024], K=4096
  moe_gemm_kernel<false, false, HID, DIM>
      <<<dim3(DIM / 128, NSLOT / 128, NEXP), 256, 0, stream>>>(
          hbf, w2t, b2, ybf, counts, offsets, idx_map);

  combine_kernel<<<T_TOK, 256, 0, stream>>>(ybf, tok_slot, tg, out);
}

// Round 3
// 943.355 us; speedup vs baseline: 1.3999x; 1.3531x over previous
//
#include <hip/hip_runtime.h>
#include <cstdio>
#include <cstdint>

// ---------------- types / helpers ----------------
typedef __attribute__((ext_vector_type(4))) float floatx4;
typedef __attribute__((ext_vector_type(8))) short short8;

constexpr int T_TOK = 8192;   // B*S
constexpr int DIM   = 1024;   // D
constexpr int NEXP  = 8;      // E
constexpr int HID   = 4096;   // H
constexpr int NSLOT = 16384;  // 2*T (top-2)
constexpr int BM = 256, BN = 128, BK = 64;
constexpr int MT_MAX = 72;    // max sum of ceil(cnt_e/256) = 64 + 7

__device__ __forceinline__ unsigned short f2bf(float f) {
  union { float f; unsigned int i; } c; c.f = f;
  unsigned int i = c.i;
  unsigned int r = (i + 0x7fffu + ((i >> 16) & 1u)) >> 16;
  return (unsigned short)r;
}
__device__ __forceinline__ float bf2f(unsigned short u) {
  union { unsigned int i; float f; } c; c.i = ((unsigned int)u) << 16;
  return c.f;
}
__device__ __forceinline__ void ld16(const void* g, void* l) {
  __builtin_amdgcn_global_load_lds(
      (const __attribute__((address_space(1))) unsigned int*)g,
      (__attribute__((address_space(3))) unsigned int*)l, 16, 0, 0);
}

// ---------------- convert x -> bf16 ----------------
__global__ __launch_bounds__(256) void convert_x_kernel(
    const float* __restrict__ x, unsigned short* __restrict__ xb, int n4) {
  int i = blockIdx.x * 256 + threadIdx.x;
  if (i < n4) {
    float4 v = ((const float4*)x)[i];
    ushort4 o;
    o.x = f2bf(v.x); o.y = f2bf(v.y); o.z = f2bf(v.z); o.w = f2bf(v.w);
    ((ushort4*)xb)[i] = o;
  }
}

// ------------- transpose+convert: fp32 [E][R][C] -> bf16 [E][C][R], 64x64 tiles -------------
// float4 global loads (16B/lane), ushort4 global stores (8B/lane, 128B/row-of-16-lanes).
// LDS scalar phases are 2 lanes/bank (free per m136).
__global__ __launch_bounds__(256) void transpose_convert_kernel(
    const float* __restrict__ in, unsigned short* __restrict__ out, int R, int C) {
  __shared__ float tile[64][65];
  int e = blockIdx.z;
  const float* ip = in + (size_t)e * R * C;
  unsigned short* op = out + (size_t)e * R * C;
  int tx = threadIdx.x & 15;    // 16 x float4 = 64 cols
  int ty = threadIdx.x >> 4;    // 0..15
  int cb = blockIdx.x * 64, rb = blockIdx.y * 64;
#pragma unroll
  for (int i = 0; i < 4; ++i) {
    int r = ty + i * 16;
    float4 v = *(const float4*)&ip[(size_t)(rb + r) * C + cb + tx * 4];
    tile[r][tx * 4 + 0] = v.x;
    tile[r][tx * 4 + 1] = v.y;
    tile[r][tx * 4 + 2] = v.z;
    tile[r][tx * 4 + 3] = v.w;
  }
  __syncthreads();
#pragma unroll
  for (int i = 0; i < 4; ++i) {
    int c = ty + i * 16;
    ushort4 o;
    o.x = f2bf(tile[tx * 4 + 0][c]);
    o.y = f2bf(tile[tx * 4 + 1][c]);
    o.z = f2bf(tile[tx * 4 + 2][c]);
    o.w = f2bf(tile[tx * 4 + 3][c]);
    *(ushort4*)&op[(size_t)(cb + c) * R + rb + tx * 4] = o;
  }
}

// ---------------- router: logits, softmax, top-2, gates, counts, prob sums ----------------
__global__ __launch_bounds__(1024) void router_kernel(
    const float* __restrict__ x, const float* __restrict__ rw, const float* __restrict__ rb,
    int* __restrict__ te, float* __restrict__ tg,
    int* __restrict__ counts, float* __restrict__ prob_sums) {
  __shared__ float ps[8];
  __shared__ int cs[8];
  int tid = threadIdx.x;
  if (tid < 8) { ps[tid] = 0.0f; cs[tid] = 0; }
  __syncthreads();
  int wid = tid >> 6, lane = tid & 63;
  int t = blockIdx.x * 16 + wid;
  const float* xt = x + (size_t)t * DIM;
  float acc[8] = {0, 0, 0, 0, 0, 0, 0, 0};
  for (int d = lane; d < DIM; d += 64) {
    float xv = xt[d];
    const float4* rp = (const float4*)(rw + d * 8);
    float4 r0 = rp[0], r1 = rp[1];
    acc[0] += xv * r0.x; acc[1] += xv * r0.y; acc[2] += xv * r0.z; acc[3] += xv * r0.w;
    acc[4] += xv * r1.x; acc[5] += xv * r1.y; acc[6] += xv * r1.z; acc[7] += xv * r1.w;
  }
#pragma unroll
  for (int e = 0; e < 8; ++e)
#pragma unroll
    for (int s = 32; s > 0; s >>= 1) acc[e] += __shfl_xor(acc[e], s, 64);
  if (lane == 0) {
    float lg[8];
#pragma unroll
    for (int e = 0; e < 8; ++e) lg[e] = acc[e] + rb[e];
    float mx = lg[0];
#pragma unroll
    for (int e = 1; e < 8; ++e) mx = fmaxf(mx, lg[e]);
    float p[8], sum = 0.0f;
#pragma unroll
    for (int e = 0; e < 8; ++e) { p[e] = __expf(lg[e] - mx); sum += p[e]; }
    float inv = 1.0f / sum;
#pragma unroll
    for (int e = 0; e < 8; ++e) p[e] *= inv;
    int i0 = 0; float v0 = p[0];
#pragma unroll
    for (int e = 1; e < 8; ++e) if (p[e] > v0) { v0 = p[e]; i0 = e; }
    int i1 = -1; float v1 = -1.0f;
#pragma unroll
    for (int e = 0; e < 8; ++e) if (e != i0 && p[e] > v1) { v1 = p[e]; i1 = e; }
    float gs = 1.0f / (v0 + v1);
    te[2 * t] = i0; te[2 * t + 1] = i1;
    tg[2 * t] = v0 * gs; tg[2 * t + 1] = v1 * gs;
    atomicAdd(&cs[i0], 1);
    atomicAdd(&cs[i1], 1);
#pragma unroll
    for (int e = 0; e < 8; ++e) atomicAdd(&ps[e], p[e]);
  }
  __syncthreads();
  if (tid < 8) {
    atomicAdd(&prob_sums[tid], ps[tid]);
    atomicAdd(&counts[tid], cs[tid]);
  }
}

// ---------------- offsets prefix + loss + GEMM tile work-list ----------------
__global__ void finalize_kernel(const int* __restrict__ counts, int* __restrict__ offsets,
                                int* __restrict__ cursor, const float* __restrict__ prob_sums,
                                float* __restrict__ loss_out,
                                int* __restrict__ tile_e, int* __restrict__ tile_tm) {
  if (threadIdx.x == 0 && blockIdx.x == 0) {
    int off = 0, nt = 0;
#pragma unroll
    for (int e = 0; e < 8; ++e) {
      offsets[e] = off; cursor[e] = off;
      int mt = (counts[e] + BM - 1) / BM;
      for (int j = 0; j < mt; ++j) { tile_e[nt] = e; tile_tm[nt] = j; ++nt; }
      off += counts[e];
    }
    for (; nt < MT_MAX; ++nt) tile_e[nt] = -1;
    float loss = 0.0f;
#pragma unroll
    for (int e = 0; e < 8; ++e) {
      float mp = prob_sums[e] * (1.0f / (float)T_TOK);
      loss += mp * logf(mp);
    }
    *loss_out = 8.0f * loss;
  }
}

// ---------------- slot assignment: two-level (LDS hist -> one global atomic per expert) ----------------
__global__ __launch_bounds__(256) void assign_kernel(
    const int* __restrict__ te, int* __restrict__ cursor,
    int* __restrict__ tok_slot, int* __restrict__ idx_map) {
  __shared__ int hist[8];
  __shared__ int base[8];
  int tid = threadIdx.x;
  if (tid < 8) hist[tid] = 0;
  __syncthreads();
  int t = blockIdx.x * 256 + tid;
  int e0 = te[2 * t], e1 = te[2 * t + 1];
  int r0 = atomicAdd(&hist[e0], 1);
  int r1 = atomicAdd(&hist[e1], 1);
  __syncthreads();
  if (tid < 8) base[tid] = atomicAdd(&cursor[tid], hist[tid]);
  __syncthreads();
  int s0 = base[e0] + r0, s1 = base[e1] + r1;
  tok_slot[2 * t] = s0; idx_map[s0] = t;
  tok_slot[2 * t + 1] = s1; idx_map[s1] = t;
}

// ---------------- MFMA GEMM: 256x128 tile, BK=64, bf16, work-list grid ----------------
// Per wave per k-iter: 64 MFMA, 24 ds_read_b128 (XOR-swizzled, conflict-free),
// 12 global_load_lds x16B staging. R2 showed 128x128 latency/barrier-bound
// (MfmaUtil 15.8%): this doubles MFMA work per barrier interval.
template <bool INDIRECT, bool GELU, int KTOT, int NTOT>
__global__ __launch_bounds__(256, 2) void moe_gemm_kernel(
    const unsigned short* __restrict__ A, const unsigned short* __restrict__ Bt,
    const float* __restrict__ bias, unsigned short* __restrict__ Out,
    const int* __restrict__ counts, const int* __restrict__ offsets,
    const int* __restrict__ idx_map,
    const int* __restrict__ tile_e, const int* __restrict__ tile_tm) {
  int e = tile_e[blockIdx.y];
  if (e < 0) return;
  int tm = tile_tm[blockIdx.y];
  int cnt = counts[e], off = offsets[e];
  int tn = blockIdx.x, tid = threadIdx.x;

  __shared__ __align__(16) unsigned short As[BM * BK];  // 32 KB
  __shared__ __align__(16) unsigned short Bs[BN * BK];  // 16 KB

  const int segp = tid & 7;                  // LDS 16B-segment position in row
  const int rsub = tid >> 3;                 // 0..31
  const int kseg = (segp ^ (rsub & 7)) * 8;  // XOR-swizzled global k-segment

  const unsigned short* aptr[8];
  const unsigned short* bptr[4];
  const unsigned short* Bte = Bt + (size_t)e * NTOT * KTOT;
#pragma unroll
  for (int c = 0; c < 8; ++c) {
    int r = c * 32 + rsub;
    int slot = off + tm * BM + r;
    long arow;
    if (INDIRECT) {
      int s = slot <= (NSLOT - 1) ? slot : (NSLOT - 1);
      arow = (long)idx_map[s] * KTOT;
    } else {
      arow = (long)slot * KTOT;
    }
    aptr[c] = A + arow + kseg;
  }
#pragma unroll
  for (int c = 0; c < 4; ++c)
    bptr[c] = Bte + (size_t)(tn * BN + c * 32 + rsub) * KTOT + kseg;

  char* ldsA = (char*)As + tid * 16;
  char* ldsB = (char*)Bs + tid * 16;

  floatx4 acc[4][8];
#pragma unroll
  for (int i = 0; i < 4; ++i)
#pragma unroll
    for (int j = 0; j < 8; ++j) acc[i][j] = (floatx4){0.f, 0.f, 0.f, 0.f};

  int wm = tid >> 6, lane = tid & 63;        // wave -> 64-row strip
  int m16 = lane & 15, q = lane >> 4;
  int sw = m16 & 7;

#pragma unroll 1
  for (int k0 = 0; k0 < KTOT; k0 += BK) {
#pragma unroll
    for (int c = 0; c < 8; ++c) ld16(aptr[c] + k0, ldsA + c * 4096);
#pragma unroll
    for (int c = 0; c < 4; ++c) ld16(bptr[c] + k0, ldsB + c * 4096);
    __syncthreads();
#pragma unroll
    for (int kk = 0; kk < 2; ++kk) {
      short8 aF[4], bF[8];
      int ko = ((kk * 4 + q) ^ sw) * 8;
#pragma unroll
      for (int mi = 0; mi < 4; ++mi)
        aF[mi] = *(const short8*)&As[(wm * 64 + mi * 16 + m16) * 64 + ko];
#pragma unroll
      for (int ni = 0; ni < 8; ++ni)
        bF[ni] = *(const short8*)&Bs[(ni * 16 + m16) * 64 + ko];
#pragma unroll
      for (int mi = 0; mi < 4; ++mi)
#pragma unroll
        for (int ni = 0; ni < 8; ++ni)
          acc[mi][ni] = __builtin_amdgcn_mfma_f32_16x16x32_bf16(
              aF[mi], bF[ni], acc[mi][ni], 0, 0, 0);
    }
    __syncthreads();
  }

  // epilogue: row-masked (ragged expert tails must not clobber packed neighbors)
  int rowlim = cnt - tm * BM;
#pragma unroll
  for (int ni = 0; ni < 8; ++ni) {
    int col = tn * BN + ni * 16 + m16;
    float bv = bias[e * NTOT + col];
#pragma unroll
    for (int mi = 0; mi < 4; ++mi) {
#pragma unroll
      for (int r = 0; r < 4; ++r) {
        int rr = wm * 64 + mi * 16 + q * 4 + r;
        if (rr < rowlim) {
          float v = acc[mi][ni][r] + bv;
          if (GELU) v = 0.5f * v * (1.0f + erff(v * 0.70710678118654752f));
          Out[(size_t)(off + tm * BM + rr) * NTOT + col] = f2bf(v);
        }
      }
    }
  }
}

// ---------------- combine: out[t] = g0*y[s0] + g1*y[s1] ----------------
__global__ __launch_bounds__(256) void combine_kernel(
    const unsigned short* __restrict__ y, const int* __restrict__ tok_slot,
    const float* __restrict__ tg, float* __restrict__ out) {
  int t = blockIdx.x;
  int s0 = tok_slot[2 * t], s1 = tok_slot[2 * t + 1];
  float g0 = tg[2 * t], g1 = tg[2 * t + 1];
  int c = threadIdx.x * 4;
  ushort4 a = *(const ushort4*)&y[(size_t)s0 * DIM + c];
  ushort4 b = *(const ushort4*)&y[(size_t)s1 * DIM + c];
  float4 o;
  o.x = g0 * bf2f(a.x) + g1 * bf2f(b.x);
  o.y = g0 * bf2f(a.y) + g1 * bf2f(b.y);
  o.z = g0 * bf2f(a.z) + g1 * bf2f(b.z);
  o.w = g0 * bf2f(a.w) + g1 * bf2f(b.w);
  ((float4*)(out + (size_t)t * DIM))[threadIdx.x] = o;
}

// ---------------- host ----------------
extern "C" void kernel_launch(void* const* d_in, const int* in_sizes, int n_in,
                              void* d_out, int out_size, void* d_ws, size_t ws_size,
                              hipStream_t stream) {
  const float* x  = (const float*)d_in[0];
  const float* rw = (const float*)d_in[1];
  const float* rb = (const float*)d_in[2];
  const float* w1 = (const float*)d_in[3];
  const float* b1 = (const float*)d_in[4];
  const float* w2 = (const float*)d_in[5];
  const float* b2 = (const float*)d_in[6];
  float* out = (float*)d_out;
  float* loss_out = out + (out_size - 1);

  size_t o = 0;
  char* wsb = (char*)d_ws;
  auto take = [&](size_t bytes) -> char* {
    char* p = wsb + o;
    o += (bytes + 255) & ~(size_t)255;
    return p;
  };
  unsigned short* w1t = (unsigned short*)take((size_t)NEXP * HID * DIM * 2);  // [E][H][D]
  unsigned short* w2t = (unsigned short*)take((size_t)NEXP * HID * DIM * 2);  // [E][D][H]
  unsigned short* xb  = (unsigned short*)take((size_t)T_TOK * DIM * 2);
  unsigned short* hbf = (unsigned short*)take((size_t)NSLOT * HID * 2 + (4u << 20)); // +4MB ragged-tail pad
  unsigned short* ybf = (unsigned short*)take((size_t)NSLOT * DIM * 2 + (1u << 20));
  int*   te       = (int*)take(NSLOT * 4);
  float* tg       = (float*)take(NSLOT * 4);
  int*   tok_slot = (int*)take(NSLOT * 4);
  int*   idx_map  = (int*)take(NSLOT * 4);
  int*   tile_e   = (int*)take(MT_MAX * 4);
  int*   tile_tm  = (int*)take(MT_MAX * 4);
  char*  smallb   = take(256);
  int*   counts    = (int*)smallb;
  float* prob_sums = (float*)(smallb + 32);
  int*   offsets   = (int*)(smallb + 64);
  int*   cursor    = (int*)(smallb + 96);

  if (o > ws_size) {
    fprintf(stderr, "kernel_launch: ws too small, need %zu have %zu\n", o, ws_size);
    return;
  }

  hipMemsetAsync(smallb, 0, 64, stream);  // counts + prob_sums

  // conversions (independent of router)
  convert_x_kernel<<<(T_TOK * DIM / 4 + 255) / 256, 256, 0, stream>>>(x, xb, T_TOK * DIM / 4);
  // w1: [E][D=1024][H=4096] -> w1t [E][H][D]
  transpose_convert_kernel<<<dim3(HID / 64, DIM / 64, NEXP), 256, 0, stream>>>(w1, w1t, DIM, HID);
  // w2: [E][H=4096][D=1024] -> w2t [E][D][H]
  transpose_convert_kernel<<<dim3(DIM / 64, HID / 64, NEXP), 256, 0, stream>>>(w2, w2t, HID, DIM);

  router_kernel<<<T_TOK / 16, 1024, 0, stream>>>(x, rw, rb, te, tg, counts, prob_sums);
  finalize_kernel<<<1, 64, 0, stream>>>(counts, offsets, cursor, prob_sums, loss_out,
                                        tile_e, tile_tm);
  assign_kernel<<<T_TOK / 256, 256, 0, stream>>>(te, cursor, tok_slot, idx_map);

  // GEMM1: h = gelu(x_gathered @ w1 + b1)   [slots x 4096], K=1024
  moe_gemm_kernel<true, true, DIM, HID>
      <<<dim3(HID / BN, MT_MAX), 256, 0, stream>>>(
          xb, w1t, b1, hbf, counts, offsets, idx_map, tile_e, tile_tm);
  // GEMM2: y = h @ w2 + b2                  [slots x 1024], K=4096
  moe_gemm_kernel<false, false, HID, DIM>
      <<<dim3(DIM / BN, MT_MAX), 256, 0, stream>>>(
          hbf, w2t, b2, ybf, counts, offsets, idx_map, tile_e, tile_tm);

  combine_kernel<<<T_TOK, 256, 0, stream>>>(ybf, tok_slot, tg, out);
}